// Round 3
// baseline (37.047 us; speedup 1.0000x reference)
//
#include <hip/hip_runtime.h>

// TimeDependentRatchetPolicyRIM: elementwise policy map, memory-bound.
// B rows; out is (B, 17) f32: [u_star[0..15]*dw_share, C].
// R3: same as R2 but nontemporal stores use a native ext_vector_type
// (clang's builtin rejects HIP_vector_type float4).

#define NCOL 17
#define BLK 256
#define RPT 2                       // rows per thread
#define ROWS (BLK * RPT)            // 512 rows per block
#define SLAB (ROWS * NCOL)          // 8704 floats per block
#define SLAB4 (SLAB / 4)            // 2176 float4 per block

typedef float f32x4 __attribute__((ext_vector_type(4)));

__global__ __launch_bounds__(BLK) void ratchet_kernel(
    const float* __restrict__ X,       // (B,2) wealth, habit
    const float* __restrict__ TmT,     // (B,)
    const float* __restrict__ y,       // (B,)
    const float* __restrict__ u_star,  // (16,)
    const float* __restrict__ s_grid,  // (2048,) linspace(0,1)
    const float* __restrict__ z_tilde, // (2048,)
    float* __restrict__ out,           // (B,17)
    long long B)
{
    __shared__ float s_dw[ROWS];
    __shared__ float s_C[ROWS];
    __shared__ float s_u[16];

    const int tid = threadIdx.x;
    const long long row0 = (long long)blockIdx.x * ROWS + (long long)tid * RPT;

    if (tid < 16) s_u[tid] = u_star[tid];

    // ---- phase 1: per-row policy compute, 2 consecutive rows ----
    // Clamped base so OOB threads read valid memory (writes are guarded).
    const long long rc = (row0 + 1 < B) ? row0 : (B - 2 >= 0 ? B - 2 : 0);

    const float4 xh2 = ((const float4*)X)[rc >> 1];        // rows rc, rc+1
    const float2 tau2 = ((const float2*)TmT)[rc >> 1];
    const float2 yv2  = ((const float2*)y)[rc >> 1];

    float wealth[RPT] = { xh2.x, xh2.z };
    float habit [RPT] = { xh2.y, xh2.w };
    float tauv  [RPT] = { tau2.x, tau2.y };
    float yval  [RPT] = { yv2.x, yv2.y };

    #pragma unroll
    for (int k = 0; k < RPT; ++k) {
        const float tau = tauv[k];
        float s = fminf(fmaxf(tau, 0.0f), 1.0f);
        int idx = (int)(s * 2047.0f);
        idx = idx < 2046 ? idx : 2046;
        idx = idx > 0 ? idx : 0;
        float g0 = s_grid[idx];
        float g1 = s_grid[idx + 1];
        if (s < g0 && idx > 0) {
            --idx; g1 = g0; g0 = s_grid[idx];
        } else if (s >= g1 && idx < 2046) {
            ++idx; g0 = g1; g1 = s_grid[idx + 1];
        }
        const float z0 = z_tilde[idx];
        const float z1 = z_tilde[idx + 1];
        const float frac = (s - g0) / (g1 - g0);
        const float z = z0 + (z1 - z0) * frac;

        const float y_eff = fmaxf(yval[k], 1e-12f);
        const float ratio = fmaxf(z / y_eff, 1e-24f);
        const float c_b   = cbrtf(ratio);            // GAMMA = 3
        const float h     = habit[k];
        const float h3    = h * h * h;
        // ALPHA_RAISE = 1 -> c_raised = c_on_boundary
        const float C     = (y_eff * h3 <= z) ? fmaxf(c_b, h) : h;
        const float ann   = (1.0f - expf(-0.02f * tau)) * 50.0f; // (1-e^-Rt)/R
        const float pvC   = ann * C;
        float dw = (wealth[k] - pvC) / fmaxf(wealth[k], 1e-12f);
        dw = fminf(fmaxf(dw, 0.0f), 1.0f);           // DW_FLOOR = 0

        s_dw[tid * RPT + k] = dw;
        s_C [tid * RPT + k] = C;
    }
    __syncthreads();

    // ---- phase 2: nontemporal coalesced float4 writes of the slab ----
    const long long slab_base = (long long)blockIdx.x * SLAB;   // in floats
    f32x4* out4 = (f32x4*)(out + slab_base);
    const long long total = B * NCOL;

    for (int m = tid; m < SLAB4; m += BLK) {
        const int e = 4 * m;
        const long long g = slab_base + e;
        float v[4];
        #pragma unroll
        for (int j = 0; j < 4; ++j) {
            const unsigned ee = (unsigned)(e + j);
            const unsigned r  = ee / 17u;
            const unsigned c  = ee - r * 17u;
            v[j] = (c < 16u) ? s_u[c] * s_dw[r] : s_C[r];
        }
        if (g + 3 < total) {
            f32x4 pack = { v[0], v[1], v[2], v[3] };
            __builtin_nontemporal_store(pack, &out4[m]);
        } else {
            for (int j = 0; j < 4 && g + j < total; ++j)
                out[g + j] = v[j];
        }
    }
}

extern "C" void kernel_launch(void* const* d_in, const int* in_sizes, int n_in,
                              void* d_out, int out_size, void* d_ws, size_t ws_size,
                              hipStream_t stream) {
    const float* X       = (const float*)d_in[0];
    const float* TmT     = (const float*)d_in[1];
    const float* y       = (const float*)d_in[2];
    const float* u_star  = (const float*)d_in[3];
    const float* s_grid  = (const float*)d_in[4];
    const float* z_tilde = (const float*)d_in[5];
    float* out = (float*)d_out;

    const long long B = in_sizes[1];  // TmT is (B,)
    const int blocks = (int)((B + ROWS - 1) / ROWS);
    ratchet_kernel<<<blocks, BLK, 0, stream>>>(X, TmT, y, u_star, s_grid,
                                               z_tilde, out, B);
}

// Round 4
// 35.436 us; speedup vs baseline: 1.0455x; 1.0455x over previous
//
#include <hip/hip_runtime.h>

// TimeDependentRatchetPolicyRIM: elementwise policy map, memory-bound.
// B rows; out is (B, 17) f32: [u_star[0..15]*dw_share, C].
// R4: RPT=2 (float4 X load, float2 TmT/y loads) + PLAIN float4 stores.
// (R3's nontemporal stores regressed 33.4 -> 37.0 us; reverted.)

#define NCOL 17
#define BLK 256
#define RPT 2                       // rows per thread
#define ROWS (BLK * RPT)            // 512 rows per block
#define SLAB (ROWS * NCOL)          // 8704 floats per block
#define SLAB4 (SLAB / 4)            // 2176 float4 per block

typedef float f32x4 __attribute__((ext_vector_type(4)));

__global__ __launch_bounds__(BLK) void ratchet_kernel(
    const float* __restrict__ X,       // (B,2) wealth, habit
    const float* __restrict__ TmT,     // (B,)
    const float* __restrict__ y,       // (B,)
    const float* __restrict__ u_star,  // (16,)
    const float* __restrict__ s_grid,  // (2048,) linspace(0,1)
    const float* __restrict__ z_tilde, // (2048,)
    float* __restrict__ out,           // (B,17)
    long long B)
{
    __shared__ float s_dw[ROWS];
    __shared__ float s_C[ROWS];
    __shared__ float s_u[16];

    const int tid = threadIdx.x;
    const long long row0 = (long long)blockIdx.x * ROWS + (long long)tid * RPT;

    if (tid < 16) s_u[tid] = u_star[tid];

    // ---- phase 1: per-row policy compute, 2 consecutive rows ----
    // Clamped base so OOB threads read valid memory (writes are guarded).
    const long long rc = (row0 + 1 < B) ? row0 : (B - 2 >= 0 ? B - 2 : 0);

    const float4 xh2 = ((const float4*)X)[rc >> 1];        // rows rc, rc+1
    const float2 tau2 = ((const float2*)TmT)[rc >> 1];
    const float2 yv2  = ((const float2*)y)[rc >> 1];

    float wealth[RPT] = { xh2.x, xh2.z };
    float habit [RPT] = { xh2.y, xh2.w };
    float tauv  [RPT] = { tau2.x, tau2.y };
    float yval  [RPT] = { yv2.x, yv2.y };

    #pragma unroll
    for (int k = 0; k < RPT; ++k) {
        const float tau = tauv[k];
        float s = fminf(fmaxf(tau, 0.0f), 1.0f);
        int idx = (int)(s * 2047.0f);
        idx = idx < 2046 ? idx : 2046;
        idx = idx > 0 ? idx : 0;
        float g0 = s_grid[idx];
        float g1 = s_grid[idx + 1];
        if (s < g0 && idx > 0) {
            --idx; g1 = g0; g0 = s_grid[idx];
        } else if (s >= g1 && idx < 2046) {
            ++idx; g0 = g1; g1 = s_grid[idx + 1];
        }
        const float z0 = z_tilde[idx];
        const float z1 = z_tilde[idx + 1];
        const float frac = (s - g0) / (g1 - g0);
        const float z = z0 + (z1 - z0) * frac;

        const float y_eff = fmaxf(yval[k], 1e-12f);
        const float ratio = fmaxf(z / y_eff, 1e-24f);
        const float c_b   = cbrtf(ratio);            // GAMMA = 3
        const float h     = habit[k];
        const float h3    = h * h * h;
        // ALPHA_RAISE = 1 -> c_raised = c_on_boundary
        const float C     = (y_eff * h3 <= z) ? fmaxf(c_b, h) : h;
        const float ann   = (1.0f - expf(-0.02f * tau)) * 50.0f; // (1-e^-Rt)/R
        const float pvC   = ann * C;
        float dw = (wealth[k] - pvC) / fmaxf(wealth[k], 1e-12f);
        dw = fminf(fmaxf(dw, 0.0f), 1.0f);           // DW_FLOOR = 0

        s_dw[tid * RPT + k] = dw;
        s_C [tid * RPT + k] = C;
    }
    __syncthreads();

    // ---- phase 2: coalesced float4 writes of the block's output slab ----
    const long long slab_base = (long long)blockIdx.x * SLAB;   // in floats
    f32x4* out4 = (f32x4*)(out + slab_base);
    const long long total = B * NCOL;

    for (int m = tid; m < SLAB4; m += BLK) {
        const int e = 4 * m;
        const long long g = slab_base + e;
        float v[4];
        #pragma unroll
        for (int j = 0; j < 4; ++j) {
            const unsigned ee = (unsigned)(e + j);
            const unsigned r  = ee / 17u;
            const unsigned c  = ee - r * 17u;
            v[j] = (c < 16u) ? s_u[c] * s_dw[r] : s_C[r];
        }
        if (g + 3 < total) {
            f32x4 pack = { v[0], v[1], v[2], v[3] };
            out4[m] = pack;
        } else {
            for (int j = 0; j < 4 && g + j < total; ++j)
                out[g + j] = v[j];
        }
    }
}

extern "C" void kernel_launch(void* const* d_in, const int* in_sizes, int n_in,
                              void* d_out, int out_size, void* d_ws, size_t ws_size,
                              hipStream_t stream) {
    const float* X       = (const float*)d_in[0];
    const float* TmT     = (const float*)d_in[1];
    const float* y       = (const float*)d_in[2];
    const float* u_star  = (const float*)d_in[3];
    const float* s_grid  = (const float*)d_in[4];
    const float* z_tilde = (const float*)d_in[5];
    float* out = (float*)d_out;

    const long long B = in_sizes[1];  // TmT is (B,)
    const int blocks = (int)((B + ROWS - 1) / ROWS);
    ratchet_kernel<<<blocks, BLK, 0, stream>>>(X, TmT, y, u_star, s_grid,
                                               z_tilde, out, B);
}

// Round 5
// 34.370 us; speedup vs baseline: 1.0779x; 1.0310x over previous
//
#include <hip/hip_runtime.h>

// TimeDependentRatchetPolicyRIM: elementwise policy map, memory-bound.
// B rows; out is (B, 17) f32: [u_star[0..15]*dw_share, C].
// R5: exact R1 structure (1 row/thread, 256-thread blocks, plain float4
// stores — best measured, 33.4us). Single change: phase-2 index math does
// ONE magic-div per float4 + carry-propagation, instead of div+mod per
// element (R3 NT stores and R4 RPT=2 both regressed; reverted).

#define NCOL 17
#define BLK 256
#define SLAB (BLK * NCOL)          // 4352 floats per block
#define SLAB4 (SLAB / 4)           // 1088 float4 per block

typedef float f32x4 __attribute__((ext_vector_type(4)));

__global__ __launch_bounds__(BLK) void ratchet_kernel(
    const float* __restrict__ X,       // (B,2) wealth, habit
    const float* __restrict__ TmT,     // (B,)
    const float* __restrict__ y,       // (B,)
    const float* __restrict__ u_star,  // (16,)
    const float* __restrict__ s_grid,  // (2048,) linspace(0,1)
    const float* __restrict__ z_tilde, // (2048,)
    float* __restrict__ out,           // (B,17)
    long long B)
{
    __shared__ float s_dw[BLK];
    __shared__ float s_C[BLK];
    __shared__ float s_u[16];

    const int tid = threadIdx.x;
    const long long row = (long long)blockIdx.x * BLK + tid;
    const long long rowc = row < B ? row : (B - 1);

    if (tid < 16) s_u[tid] = u_star[tid];

    // ---- phase 1: per-row policy compute ----
    const float2 xh = ((const float2*)X)[rowc];
    const float wealth = xh.x;
    const float habit  = xh.y;
    const float tau    = TmT[rowc];
    const float yv     = y[rowc];

    // z_tau = interp(clip(tau,0,1), s_grid, z_tilde); uniform grid + refine
    float s = fminf(fmaxf(tau, 0.0f), 1.0f);
    int idx = (int)(s * 2047.0f);
    idx = idx < 2046 ? idx : 2046;
    idx = idx > 0 ? idx : 0;
    float g0 = s_grid[idx];
    float g1 = s_grid[idx + 1];
    if (s < g0 && idx > 0) {
        --idx; g1 = g0; g0 = s_grid[idx];
    } else if (s >= g1 && idx < 2046) {
        ++idx; g0 = g1; g1 = s_grid[idx + 1];
    }
    const float z0 = z_tilde[idx];
    const float z1 = z_tilde[idx + 1];
    const float frac = (s - g0) / (g1 - g0);
    const float z = z0 + (z1 - z0) * frac;

    const float y_eff = fmaxf(yv, 1e-12f);
    const float ratio = fmaxf(z / y_eff, 1e-24f);
    const float c_b   = cbrtf(ratio);            // GAMMA = 3
    const float h3    = habit * habit * habit;
    // ALPHA_RAISE = 1 -> c_raised = c_on_boundary
    const float C     = (y_eff * h3 <= z) ? fmaxf(c_b, habit) : habit;
    const float ann   = (1.0f - expf(-0.02f * tau)) * 50.0f;  // (1-e^{-R tau})/R
    const float pvC   = ann * C;
    float dw = (wealth - pvC) / fmaxf(wealth, 1e-12f);
    dw = fminf(fmaxf(dw, 0.0f), 1.0f);           // DW_FLOOR = 0

    s_dw[tid] = dw;
    s_C[tid]  = C;
    __syncthreads();

    // ---- phase 2: coalesced float4 writes of the block's output slab ----
    const long long slab_base = (long long)blockIdx.x * SLAB;   // in floats
    f32x4* out4 = (f32x4*)(out + slab_base);
    const long long total = B * NCOL;

    for (int m = tid; m < SLAB4; m += BLK) {
        const int e = 4 * m;
        const long long g = slab_base + e;
        // one division per float4; carry-propagate across the 4 elements
        unsigned r = (unsigned)e / 17u;
        unsigned c = (unsigned)e - r * 17u;
        float v[4];
        #pragma unroll
        for (int j = 0; j < 4; ++j) {
            unsigned cj = c + (unsigned)j;
            unsigned rj = r;
            if (cj >= 17u) { cj -= 17u; rj += 1u; }
            v[j] = (cj < 16u) ? s_u[cj] * s_dw[rj] : s_C[rj];
        }
        if (g + 3 < total) {
            f32x4 pack = { v[0], v[1], v[2], v[3] };
            out4[m] = pack;
        } else {
            for (int j = 0; j < 4 && g + j < total; ++j)
                out[g + j] = v[j];
        }
    }
}

extern "C" void kernel_launch(void* const* d_in, const int* in_sizes, int n_in,
                              void* d_out, int out_size, void* d_ws, size_t ws_size,
                              hipStream_t stream) {
    const float* X       = (const float*)d_in[0];
    const float* TmT     = (const float*)d_in[1];
    const float* y       = (const float*)d_in[2];
    const float* u_star  = (const float*)d_in[3];
    const float* s_grid  = (const float*)d_in[4];
    const float* z_tilde = (const float*)d_in[5];
    float* out = (float*)d_out;

    const long long B = in_sizes[1];  // TmT is (B,)
    const int blocks = (int)((B + BLK - 1) / BLK);
    ratchet_kernel<<<blocks, BLK, 0, stream>>>(X, TmT, y, u_star, s_grid,
                                               z_tilde, out, B);
}

// Round 6
// 34.277 us; speedup vs baseline: 1.0808x; 1.0027x over previous
//
#include <hip/hip_runtime.h>

// TimeDependentRatchetPolicyRIM: elementwise policy map, memory-bound.
// B rows; out is (B, 17) f32: [u_star[0..15]*dw_share, C].
// R6: R1 structure (best measured, 33.4us: 1 row/thread, 256-thread blocks,
// LDS-staged slab, plain float4 stores). Single change: B%256==0 in this
// problem, so the EXACT path drops ALL tail guards and fully unrolls phase 2
// into 4 unconditional stores + 1 (tid<64) store. Generic fallback retained.
// Ledger: R3 NT stores 37.0 (revert), R4 RPT=2 35.4 (revert), R5 carry 34.4.

#define NCOL 17
#define BLK 256
#define SLAB (BLK * NCOL)          // 4352 floats per block
#define SLAB4 (SLAB / 4)           // 1088 float4 per block; 1088 = 4*256 + 64

typedef float f32x4 __attribute__((ext_vector_type(4)));

template<bool EXACT>
__global__ __launch_bounds__(BLK) void ratchet_kernel(
    const float* __restrict__ X,       // (B,2) wealth, habit
    const float* __restrict__ TmT,     // (B,)
    const float* __restrict__ y,       // (B,)
    const float* __restrict__ u_star,  // (16,)
    const float* __restrict__ s_grid,  // (2048,) linspace(0,1)
    const float* __restrict__ z_tilde, // (2048,)
    float* __restrict__ out,           // (B,17)
    long long B)
{
    __shared__ float s_dw[BLK];
    __shared__ float s_C[BLK];
    __shared__ float s_u[16];

    const int tid = threadIdx.x;
    const long long row = (long long)blockIdx.x * BLK + tid;
    const long long rowc = (EXACT || row < B) ? row : (B - 1);

    if (tid < 16) s_u[tid] = u_star[tid];

    // ---- phase 1: per-row policy compute ----
    const float2 xh = ((const float2*)X)[rowc];
    const float wealth = xh.x;
    const float habit  = xh.y;
    const float tau    = TmT[rowc];
    const float yv     = y[rowc];

    // z_tau = interp(clip(tau,0,1), s_grid, z_tilde); uniform grid + refine
    float s = fminf(fmaxf(tau, 0.0f), 1.0f);
    int idx = (int)(s * 2047.0f);
    idx = idx < 2046 ? idx : 2046;
    idx = idx > 0 ? idx : 0;
    float g0 = s_grid[idx];
    float g1 = s_grid[idx + 1];
    if (s < g0 && idx > 0) {
        --idx; g1 = g0; g0 = s_grid[idx];
    } else if (s >= g1 && idx < 2046) {
        ++idx; g0 = g1; g1 = s_grid[idx + 1];
    }
    const float z0 = z_tilde[idx];
    const float z1 = z_tilde[idx + 1];
    const float frac = (s - g0) / (g1 - g0);
    const float z = z0 + (z1 - z0) * frac;

    const float y_eff = fmaxf(yv, 1e-12f);
    const float ratio = fmaxf(z / y_eff, 1e-24f);
    const float c_b   = cbrtf(ratio);            // GAMMA = 3
    const float h3    = habit * habit * habit;
    // ALPHA_RAISE = 1 -> c_raised = c_on_boundary
    const float C     = (y_eff * h3 <= z) ? fmaxf(c_b, habit) : habit;
    const float ann   = (1.0f - expf(-0.02f * tau)) * 50.0f;  // (1-e^{-R tau})/R
    const float pvC   = ann * C;
    float dw = (wealth - pvC) / fmaxf(wealth, 1e-12f);
    dw = fminf(fmaxf(dw, 0.0f), 1.0f);           // DW_FLOOR = 0

    s_dw[tid] = dw;
    s_C[tid]  = C;
    __syncthreads();

    // ---- phase 2: coalesced float4 writes of the block's output slab ----
    const long long slab_base = (long long)blockIdx.x * SLAB;   // in floats
    f32x4* out4 = (f32x4*)(out + slab_base);

    if (EXACT) {
        // Full slab guaranteed in-range: 4 unconditional stores + 1 partial.
        #pragma unroll
        for (int it = 0; it < 4; ++it) {
            const int m = tid + it * BLK;
            const int e = 4 * m;
            float v[4];
            #pragma unroll
            for (int j = 0; j < 4; ++j) {
                const unsigned ee = (unsigned)(e + j);
                const unsigned r  = ee / 17u;
                const unsigned c  = ee - r * 17u;
                v[j] = (c < 16u) ? s_u[c] * s_dw[r] : s_C[r];
            }
            f32x4 pack = { v[0], v[1], v[2], v[3] };
            out4[m] = pack;
        }
        if (tid < SLAB4 - 4 * BLK) {               // 64 threads
            const int m = tid + 4 * BLK;
            const int e = 4 * m;
            float v[4];
            #pragma unroll
            for (int j = 0; j < 4; ++j) {
                const unsigned ee = (unsigned)(e + j);
                const unsigned r  = ee / 17u;
                const unsigned c  = ee - r * 17u;
                v[j] = (c < 16u) ? s_u[c] * s_dw[r] : s_C[r];
            }
            f32x4 pack = { v[0], v[1], v[2], v[3] };
            out4[m] = pack;
        }
    } else {
        const long long total = B * NCOL;
        for (int m = tid; m < SLAB4; m += BLK) {
            const int e = 4 * m;
            const long long g = slab_base + e;
            float v[4];
            #pragma unroll
            for (int j = 0; j < 4; ++j) {
                const unsigned ee = (unsigned)(e + j);
                const unsigned r  = ee / 17u;
                const unsigned c  = ee - r * 17u;
                v[j] = (c < 16u) ? s_u[c] * s_dw[r] : s_C[r];
            }
            if (g + 3 < total) {
                f32x4 pack = { v[0], v[1], v[2], v[3] };
                out4[m] = pack;
            } else {
                for (int j = 0; j < 4 && g + j < total; ++j)
                    out[g + j] = v[j];
            }
        }
    }
}

extern "C" void kernel_launch(void* const* d_in, const int* in_sizes, int n_in,
                              void* d_out, int out_size, void* d_ws, size_t ws_size,
                              hipStream_t stream) {
    const float* X       = (const float*)d_in[0];
    const float* TmT     = (const float*)d_in[1];
    const float* y       = (const float*)d_in[2];
    const float* u_star  = (const float*)d_in[3];
    const float* s_grid  = (const float*)d_in[4];
    const float* z_tilde = (const float*)d_in[5];
    float* out = (float*)d_out;

    const long long B = in_sizes[1];  // TmT is (B,)
    const int blocks = (int)((B + BLK - 1) / BLK);
    if (B % BLK == 0) {
        ratchet_kernel<true><<<blocks, BLK, 0, stream>>>(
            X, TmT, y, u_star, s_grid, z_tilde, out, B);
    } else {
        ratchet_kernel<false><<<blocks, BLK, 0, stream>>>(
            X, TmT, y, u_star, s_grid, z_tilde, out, B);
    }
}